// Round 4
// baseline (2597.683 us; speedup 1.0000x reference)
//
#include <hip/hip_runtime.h>
#include <math.h>

#define B_  4
#define S_  4096
#define E_  2048
#define M_  2048
#define ROWS (B_*S_)              // 16384
#define DECAYF 0.95f
#define SCALEF 0.22360679774997896f   // sqrt(1-0.95)
#define CH 128
#define NC 32                     // S_/CH

typedef __attribute__((ext_vector_type(8))) __bf16 bf16x8;
typedef __attribute__((ext_vector_type(4))) float f32x4;
typedef unsigned short u16;

__device__ __forceinline__ u16 f2bf(float f) {
  unsigned u = __float_as_uint(f);
  u += 0x7FFF + ((u >> 16) & 1);      // RNE
  return (u16)(u >> 16);
}
__device__ __forceinline__ float bf2f(u16 h) {
  return __uint_as_float(((unsigned)h) << 16);
}
__device__ __forceinline__ float sigmoidf_(float x) {
  return 1.0f / (1.0f + expf(-x));
}

// ---------- beacon: ws too small -> unmistakable absmax ~1e6 ----------
__global__ void beacon_kernel(float* __restrict__ out) {
  out[threadIdx.x] = 1.0e6f;
}

// ---------- split x (fp32) -> bf16 hi (+ optional lo) ----------
__global__ void split_x_kernel(const float* __restrict__ x, u16* __restrict__ hi,
                               u16* __restrict__ lo, size_t n4) {
  size_t i = (size_t)blockIdx.x * blockDim.x + threadIdx.x;
  size_t stride = (size_t)gridDim.x * blockDim.x;
  const float4* x4 = (const float4*)x;
  for (; i < n4; i += stride) {
    float4 v = x4[i];
    u16 h0 = f2bf(v.x), h1 = f2bf(v.y), h2 = f2bf(v.z), h3 = f2bf(v.w);
    ushort4 hv = {h0, h1, h2, h3};
    ((ushort4*)hi)[i] = hv;
    if (lo) {
      ushort4 lv = {f2bf(v.x - bf2f(h0)), f2bf(v.y - bf2f(h1)),
                    f2bf(v.z - bf2f(h2)), f2bf(v.w - bf2f(h3))};
      ((ushort4*)lo)[i] = lv;
    }
  }
}

// ---------- transpose + split W[K][N] fp32 -> Wt_hi/lo [N][K] bf16 ----------
__global__ void splitT_kernel(const float* __restrict__ W, u16* __restrict__ th,
                              u16* __restrict__ tl) {
  __shared__ float tile[32][33];
  int k0 = blockIdx.x * 32, n0 = blockIdx.y * 32;
  int tx = threadIdx.x & 31, ty = threadIdx.x >> 5;   // 256 threads
  #pragma unroll
  for (int i = ty; i < 32; i += 8)
    tile[i][tx] = W[(size_t)(k0 + i) * M_ + (n0 + tx)];
  __syncthreads();
  #pragma unroll
  for (int i = ty; i < 32; i += 8) {
    float v = tile[tx][i];                 // = W[k0+tx][n0+i]
    size_t o = (size_t)(n0 + i) * E_ + (k0 + tx);
    u16 h = f2bf(v);
    th[o] = h;
    tl[o] = f2bf(v - bf2f(h));
  }
}

// ---------- split-bf16 GEMM, m97 structure + XCD swizzle (T1) ----------
// acc = sum of NTERMS unit-GEMMs over K:
//   NTERMS==3: A0*B0 + A1*B0 + A0*B1   (full split, ~fp32 accurate)
//   NTERMS==2: A0*B0 + A0*B1           (A already bf16)
// A: [Mrows][K] bf16, B: [N][K] bf16 (i.e. B^T, K-contiguous).
// 128x128 tile, BK=32, 256 threads. Grid 1D, multiple of 8.
#define BK 32
template<int NTERMS, bool OUT_BF16>
__global__ __launch_bounds__(256) void gemm_split_bt(
    const u16* __restrict__ A0, const u16* __restrict__ A1,
    const u16* __restrict__ B0, const u16* __restrict__ B1,
    void* __restrict__ Cout, int Mrows, int N, int K) {
  __shared__ __align__(16) u16 As[128 * BK];
  __shared__ __align__(16) u16 Bs[128 * BK];

  // bijective XCD swizzle (gridDim.x % 8 == 0)
  const int cpx = gridDim.x >> 3;
  const int swz = (blockIdx.x & 7) * cpx + (blockIdx.x >> 3);
  const int mtiles = Mrows >> 7;
  const int bm = (swz % mtiles) * 128;     // m fastest: same-XCD blocks share bn
  const int bn = (swz / mtiles) * 128;

  const int t = threadIdx.x;
  const int wave = t >> 6, lane = t & 63;
  const int wr = wave >> 1, wc = wave & 1;        // 2x2 wave grid, 64x64 each
  const int lr = lane & 15, lk = (lane >> 4) * 8; // fragment row + k-offset
  const int srow = (lane >> 2);                   // staging: 4 lanes/row
  const int scol = (lane & 3) * 8;

  f32x4 acc[4][4];
  #pragma unroll
  for (int i = 0; i < 4; ++i)
    #pragma unroll
    for (int j = 0; j < 4; ++j)
      acc[i][j] = f32x4{0.f, 0.f, 0.f, 0.f};

  const int KT = K / BK;
  const int NKT = KT * NTERMS;

  auto stage = [&](int it) {
    const int term = it / KT;
    const int kk = (it - term * KT) * BK;
    const u16* Ab;
    const u16* Bb;
    if (NTERMS == 3) { Ab = (term == 1) ? A1 : A0; Bb = (term == 2) ? B1 : B0; }
    else             { Ab = A0;                    Bb = (term == 1) ? B1 : B0; }
    #pragma unroll
    for (int j = 0; j < 2; ++j) {
      // wave w stages rows [32w+16j, 32w+16j+16); LDS dest = base + lane*16B
      __builtin_amdgcn_global_load_lds(
          (const __attribute__((address_space(1))) unsigned int*)
              (Ab + (size_t)(bm + wave * 32 + j * 16 + srow) * K + kk + scol),
          (__attribute__((address_space(3))) unsigned int*)
              (As + wave * 1024 + j * 512),
          16, 0, 0);
      __builtin_amdgcn_global_load_lds(
          (const __attribute__((address_space(1))) unsigned int*)
              (Bb + (size_t)(bn + wave * 32 + j * 16 + srow) * K + kk + scol),
          (__attribute__((address_space(3))) unsigned int*)
              (Bs + wave * 1024 + j * 512),
          16, 0, 0);
    }
  };

  stage(0);
  for (int it = 0; it < NKT; ++it) {
    __syncthreads();                     // drains vmcnt(0): tile resident
    bf16x8 af[4], bfr[4];
    #pragma unroll
    for (int i = 0; i < 4; ++i) {
      af[i]  = *(const bf16x8*)&As[(wr * 64 + i * 16 + lr) * BK + lk];
      bfr[i] = *(const bf16x8*)&Bs[(wc * 64 + i * 16 + lr) * BK + lk];
    }
    #pragma unroll
    for (int i = 0; i < 4; ++i)
      #pragma unroll
      for (int j = 0; j < 4; ++j)
        acc[i][j] = __builtin_amdgcn_mfma_f32_16x16x32_bf16(af[i], bfr[j],
                                                            acc[i][j], 0, 0, 0);
    __syncthreads();                     // reads done before overwrite
    if (it + 1 < NKT) stage(it + 1);
  }

  // epilogue: C/D layout col=lane&15, row=(lane>>4)*4+reg  [m89-verified]
  #pragma unroll
  for (int i = 0; i < 4; ++i) {
    #pragma unroll
    for (int j = 0; j < 4; ++j) {
      const int r0 = bm + wr * 64 + i * 16 + (lane >> 4) * 4;
      const int c  = bn + wc * 64 + j * 16 + lr;
      #pragma unroll
      for (int r = 0; r < 4; ++r) {
        if (OUT_BF16) ((u16*)Cout)[(size_t)(r0 + r) * N + c] = f2bf(acc[i][j][r]);
        else          ((float*)Cout)[(size_t)(r0 + r) * N + c] = acc[i][j][r];
      }
    }
  }
}

// ---------- decay scan, 3-phase chunked (C-buffers are bf16 z-values) ----------
__global__ void scan_p1(const u16* __restrict__ Cg, const u16* __restrict__ Cv,
                        const float* __restrict__ bg, float* __restrict__ E) {
  int tid = blockIdx.x * blockDim.x + threadIdx.x;  // B_*NC*M_
  int m = tid & (M_ - 1);
  int bc = tid >> 11;
  int c = bc & (NC - 1);
  int b = bc >> 5;
  float bgm = bg[m];
  size_t base = ((size_t)b * S_ + (size_t)c * CH) * M_ + m;
  float e = 0.f;
  #pragma unroll 4
  for (int s = 0; s < CH; ++s) {
    size_t o = base + (size_t)s * M_;
    float st = bf2f(Cv[o]) * sigmoidf_(bf2f(Cg[o]) + bgm) * SCALEF;
    e = fmaf(DECAYF, e, st);
  }
  E[(size_t)(b * M_ + m) * NC + c] = e;
}

__global__ void scan_p2(const float* __restrict__ E, float* __restrict__ P, float dch) {
  int tid = blockIdx.x * blockDim.x + threadIdx.x;  // B_*M_
  if (tid >= B_ * M_) return;
  size_t base = (size_t)tid * NC;
  float p = 0.f;
  for (int c = 0; c < NC; ++c) {
    P[base + c] = p;                    // carry INTO chunk c
    p = E[base + c] + dch * p;
  }
}

__global__ void scan_p3(const u16* __restrict__ Cg, const u16* __restrict__ Cv,
                        const u16* __restrict__ Cq, const float* __restrict__ bg,
                        const float* __restrict__ bq, const float* __restrict__ P,
                        u16* __restrict__ Lhi) {
  int tid = blockIdx.x * blockDim.x + threadIdx.x;
  int m = tid & (M_ - 1);
  int bc = tid >> 11;
  int c = bc & (NC - 1);
  int b = bc >> 5;
  float bgm = bg[m], bqm = bq[m];
  float mem = P[(size_t)(b * M_ + m) * NC + c];
  size_t base = ((size_t)b * S_ + (size_t)c * CH) * M_ + m;
  #pragma unroll 4
  for (int s = 0; s < CH; ++s) {
    size_t o = base + (size_t)s * M_;
    float st = bf2f(Cv[o]) * sigmoidf_(bf2f(Cg[o]) + bgm) * SCALEF;
    mem = fmaf(DECAYF, mem, st);
    float ld = mem * sigmoidf_(bf2f(Cq[o]) + bqm) * SCALEF;
    Lhi[o] = f2bf(ld);
  }
}

extern "C" void kernel_launch(void* const* d_in, const int* in_sizes, int n_in,
                              void* d_out, int out_size, void* d_ws, size_t ws_size,
                              hipStream_t stream) {
  const float* x  = (const float*)d_in[0];
  const float* Wv = (const float*)d_in[1];
  const float* Wg = (const float*)d_in[2];
  const float* bg = (const float*)d_in[3];
  const float* Wq = (const float*)d_in[4];
  const float* bq = (const float*)d_in[5];
  const float* Wo = (const float*)d_in[6];
  float* out = (float*)d_out;

  const size_t NXE = (size_t)ROWS * E_;   // 33.5M elems
  const size_t NW  = (size_t)E_ * M_;     // 4.2M elems

  char* ws = (char*)d_ws;
  size_t off = 0;
  auto alloc = [&](size_t bytes) -> void* {
    void* p = ws + off;
    off += (bytes + 255) & ~(size_t)255;
    return p;
  };
  // ---- core allocations (~270 MB) ----
  u16* x_hi   = (u16*)alloc(NXE * 2);     // aliased as Lhi after projections
  u16* Wgt_hi = (u16*)alloc(NW * 2);
  u16* Wgt_lo = (u16*)alloc(NW * 2);
  u16* Wvt_hi = (u16*)alloc(NW * 2);
  u16* Wvt_lo = (u16*)alloc(NW * 2);
  u16* Wqt_hi = (u16*)alloc(NW * 2);
  u16* Wqt_lo = (u16*)alloc(NW * 2);
  u16* Wot_hi = (u16*)alloc(NW * 2);
  u16* Wot_lo = (u16*)alloc(NW * 2);
  u16* Cg16   = (u16*)alloc(NXE * 2);
  u16* Cv16   = (u16*)alloc(NXE * 2);
  float* Ebuf = (float*)alloc((size_t)B_ * M_ * NC * 4);
  float* Pbuf = (float*)alloc((size_t)B_ * M_ * NC * 4);
  if (off > ws_size) {                    // ws < ~270MB: loud failure
    beacon_kernel<<<1, 256, 0, stream>>>(out);
    return;
  }
  // ---- tier 1: Cq16 in ws if it fits, else in d_out (consumed before GEMM4 writes) ----
  u16* Cq16;
  if (off + NXE * 2 <= ws_size) Cq16 = (u16*)alloc(NXE * 2);
  else                          Cq16 = (u16*)d_out;   // 67MB < 128MB out buffer
  // ---- tier 2: x_lo (3-term projections) if it fits ----
  u16* x_lo = nullptr;
  if (off + NXE * 2 <= ws_size) x_lo = (u16*)alloc(NXE * 2);
  // Lhi aliases x_hi (x dead after the projection GEMMs)
  u16* Lhi = x_hi;

  // 1) precision-split inputs
  split_x_kernel<<<2048, 256, 0, stream>>>(x, x_hi, x_lo, NXE / 4);
  dim3 tg(E_ / 32, M_ / 32);
  splitT_kernel<<<tg, 256, 0, stream>>>(Wg, Wgt_hi, Wgt_lo);
  splitT_kernel<<<tg, 256, 0, stream>>>(Wv, Wvt_hi, Wvt_lo);
  splitT_kernel<<<tg, 256, 0, stream>>>(Wq, Wqt_hi, Wqt_lo);
  splitT_kernel<<<tg, 256, 0, stream>>>(Wo, Wot_hi, Wot_lo);

  // 2) three projection GEMMs -> bf16 z-buffers
  const int ngemm = (ROWS / 128) * (M_ / 128);   // 2048, % 8 == 0
  if (x_lo) {
    gemm_split_bt<3, true><<<ngemm, 256, 0, stream>>>(x_hi, x_lo, Wgt_hi, Wgt_lo, Cg16, ROWS, M_, E_);
    gemm_split_bt<3, true><<<ngemm, 256, 0, stream>>>(x_hi, x_lo, Wvt_hi, Wvt_lo, Cv16, ROWS, M_, E_);
    gemm_split_bt<3, true><<<ngemm, 256, 0, stream>>>(x_hi, x_lo, Wqt_hi, Wqt_lo, Cq16, ROWS, M_, E_);
  } else {
    gemm_split_bt<2, true><<<ngemm, 256, 0, stream>>>(x_hi, x_hi, Wgt_hi, Wgt_lo, Cg16, ROWS, M_, E_);
    gemm_split_bt<2, true><<<ngemm, 256, 0, stream>>>(x_hi, x_hi, Wvt_hi, Wvt_lo, Cv16, ROWS, M_, E_);
    gemm_split_bt<2, true><<<ngemm, 256, 0, stream>>>(x_hi, x_hi, Wqt_hi, Wqt_lo, Cq16, ROWS, M_, E_);
  }

  // 3) fused gate/store -> chunked decay scan -> que/load (bf16, into Lhi==x_hi)
  scan_p1<<<(B_ * NC * M_) / 256, 256, 0, stream>>>(Cg16, Cv16, bg, Ebuf);
  scan_p2<<<(B_ * M_ + 255) / 256, 256, 0, stream>>>(Ebuf, Pbuf, powf(DECAYF, (float)CH));
  scan_p3<<<(B_ * NC * M_) / 256, 256, 0, stream>>>(Cg16, Cv16, Cq16, bg, bq, Pbuf, Lhi);

  // 4) output projection (fp32 out, 2-term: L*Wo_hi + L*Wo_lo)
  gemm_split_bt<2, false><<<ngemm, 256, 0, stream>>>(Lhi, Lhi, Wot_hi, Wot_lo, out, ROWS, E_, M_);
}

// Round 6
// 1777.404 us; speedup vs baseline: 1.4615x; 1.4615x over previous
//
#include <hip/hip_runtime.h>
#include <math.h>

#define B_  4
#define S_  4096
#define E_  2048
#define M_  2048
#define ROWS (B_*S_)              // 16384
#define DECAYF 0.95f
#define SCALEF 0.22360679774997896f   // sqrt(1-0.95)
#define CH 128
#define NC 32                     // S_/CH

typedef __attribute__((ext_vector_type(8))) __bf16 bf16x8;
typedef __attribute__((ext_vector_type(4))) float f32x4;
typedef unsigned short u16;

__device__ __forceinline__ u16 f2bf(float f) {
  unsigned u = __float_as_uint(f);
  u += 0x7FFF + ((u >> 16) & 1);      // RNE
  return (u16)(u >> 16);
}
__device__ __forceinline__ float bf2f(u16 h) {
  return __uint_as_float(((unsigned)h) << 16);
}
__device__ __forceinline__ float sigmoidf_(float x) {
  return 1.0f / (1.0f + expf(-x));
}

// ---------- beacon: ws too small -> unmistakable absmax ~1e6 ----------
__global__ void beacon_kernel(float* __restrict__ out) {
  out[threadIdx.x] = 1.0e6f;
}

// ---------- split x (fp32) -> bf16 hi (+ optional lo) ----------
__global__ void split_x_kernel(const float* __restrict__ x, u16* __restrict__ hi,
                               u16* __restrict__ lo, size_t n4) {
  size_t i = (size_t)blockIdx.x * blockDim.x + threadIdx.x;
  size_t stride = (size_t)gridDim.x * blockDim.x;
  const float4* x4 = (const float4*)x;
  for (; i < n4; i += stride) {
    float4 v = x4[i];
    u16 h0 = f2bf(v.x), h1 = f2bf(v.y), h2 = f2bf(v.z), h3 = f2bf(v.w);
    ushort4 hv = {h0, h1, h2, h3};
    ((ushort4*)hi)[i] = hv;
    if (lo) {
      ushort4 lv = {f2bf(v.x - bf2f(h0)), f2bf(v.y - bf2f(h1)),
                    f2bf(v.z - bf2f(h2)), f2bf(v.w - bf2f(h3))};
      ((ushort4*)lo)[i] = lv;
    }
  }
}

// ---------- transpose + split W[K][N] fp32 -> Wt_hi/lo [N][K] bf16 ----------
__global__ void splitT_kernel(const float* __restrict__ W, u16* __restrict__ th,
                              u16* __restrict__ tl) {
  __shared__ float tile[32][33];
  int k0 = blockIdx.x * 32, n0 = blockIdx.y * 32;
  int tx = threadIdx.x & 31, ty = threadIdx.x >> 5;   // 256 threads
  #pragma unroll
  for (int i = ty; i < 32; i += 8)
    tile[i][tx] = W[(size_t)(k0 + i) * M_ + (n0 + tx)];
  __syncthreads();
  #pragma unroll
  for (int i = ty; i < 32; i += 8) {
    float v = tile[tx][i];                 // = W[k0+tx][n0+i]
    size_t o = (size_t)(n0 + i) * E_ + (k0 + tx);
    u16 h = f2bf(v);
    th[o] = h;
    tl[o] = f2bf(v - bf2f(h));
  }
}

// ---------- split-bf16 GEMM, term-interleaved, bn-fastest XCD swizzle ----------
// acc = sum over K of:
//   NTERMS==3: A0*B0 + A1*B0 + A0*B1   (full split, ~fp32 accurate)
//   NTERMS==2: A0*B0 + A0*B1           (A already bf16)
// All terms for one K-chunk staged together: 48 (or 32) MFMA per barrier-pair
// instead of 16 -> 3x fewer vmcnt(0) drains per unit work.
// A: [Mrows][K] bf16, B: [N][K] bf16. 128x128 tile, BK=32, 256 threads.
#define BK 32
template<int NTERMS, bool OUT_BF16>
__global__ __launch_bounds__(256) void gemm_split_bt(
    const u16* __restrict__ A0, const u16* __restrict__ A1,
    const u16* __restrict__ B0, const u16* __restrict__ B1,
    void* __restrict__ Cout, int Mrows, int N, int K) {
  constexpr int TILE = 128 * BK;           // 4096 u16 = 8 KB
  constexpr int NT = NTERMS + 1;           // tiles staged per K-chunk
  __shared__ __align__(16) u16 sm[NT * TILE];
  u16* const As0 = sm;
  u16* const As1 = sm + TILE;                              // 3-term only
  u16* const Bs0 = sm + (NTERMS == 3 ? 2 : 1) * TILE;
  u16* const Bs1 = sm + (NTERMS == 3 ? 3 : 2) * TILE;

  // bijective XCD swizzle (gridDim.x % 8 == 0), bn FASTEST within an XCD:
  // XCD x owns a contiguous 16-m-tile A-slice (L2/L3-resident, each A-tile
  // reused by 16 adjacent blocks); B is small (17 MB hi+lo) -> L3-resident.
  const int cpx = gridDim.x >> 3;
  const int swz = (blockIdx.x & 7) * cpx + (blockIdx.x >> 3);
  const int ntiles = N >> 7;
  const int bm = (swz / ntiles) * 128;
  const int bn = (swz % ntiles) * 128;

  const int t = threadIdx.x;
  const int wave = t >> 6, lane = t & 63;
  const int wr = wave >> 1, wc = wave & 1;        // 2x2 wave grid, 64x64 each
  const int lr = lane & 15, lk = (lane >> 4) * 8; // fragment row + k-offset
  const int srow = (lane >> 2);                   // staging: 4 lanes/row
  const int scol = (lane & 3) * 8;

  f32x4 acc[4][4];
  #pragma unroll
  for (int i = 0; i < 4; ++i)
    #pragma unroll
    for (int j = 0; j < 4; ++j)
      acc[i][j] = f32x4{0.f, 0.f, 0.f, 0.f};

  const int KT = K / BK;

  auto stage_tile = [&](const u16* src, u16* dst, int brow, int kk) {
    #pragma unroll
    for (int j = 0; j < 2; ++j) {
      // wave w stages rows [32w+16j, 32w+16j+16); LDS dest = base + lane*16B
      __builtin_amdgcn_global_load_lds(
          (const __attribute__((address_space(1))) unsigned int*)
              (src + (size_t)(brow + wave * 32 + j * 16 + srow) * K + kk + scol),
          (__attribute__((address_space(3))) unsigned int*)
              (dst + wave * 1024 + j * 512),
          16, 0, 0);
    }
  };
  auto stage = [&](int it) {
    const int kk = it * BK;
    stage_tile(A0, As0, bm, kk);
    if (NTERMS == 3) stage_tile(A1, As1, bm, kk);
    stage_tile(B0, Bs0, bn, kk);
    stage_tile(B1, Bs1, bn, kk);
  };

  stage(0);
  for (int it = 0; it < KT; ++it) {
    __syncthreads();                     // drains vmcnt(0): tiles resident
    bf16x8 a0[4], a1[4], b0[4], b1[4];
    #pragma unroll
    for (int i = 0; i < 4; ++i) {
      const int ro = (i * 16 + lr) * BK + lk;
      a0[i] = *(const bf16x8*)&As0[wr * 64 * BK + ro];
      if (NTERMS == 3) a1[i] = *(const bf16x8*)&As1[wr * 64 * BK + ro];
      b0[i] = *(const bf16x8*)&Bs0[wc * 64 * BK + ro];
      b1[i] = *(const bf16x8*)&Bs1[wc * 64 * BK + ro];
    }
    #pragma unroll
    for (int i = 0; i < 4; ++i)
      #pragma unroll
      for (int j = 0; j < 4; ++j) {
        acc[i][j] = __builtin_amdgcn_mfma_f32_16x16x32_bf16(a0[i], b0[j],
                                                            acc[i][j], 0, 0, 0);
        if (NTERMS == 3)
          acc[i][j] = __builtin_amdgcn_mfma_f32_16x16x32_bf16(a1[i], b0[j],
                                                              acc[i][j], 0, 0, 0);
        acc[i][j] = __builtin_amdgcn_mfma_f32_16x16x32_bf16(a0[i], b1[j],
                                                            acc[i][j], 0, 0, 0);
      }
    __syncthreads();                     // reads done before overwrite
    if (it + 1 < KT) stage(it + 1);
  }

  // epilogue: C/D layout col=lane&15, row=(lane>>4)*4+reg  [m89-verified]
  #pragma unroll
  for (int i = 0; i < 4; ++i) {
    #pragma unroll
    for (int j = 0; j < 4; ++j) {
      const int r0 = bm + wr * 64 + i * 16 + (lane >> 4) * 4;
      const int c  = bn + wc * 64 + j * 16 + lr;
      #pragma unroll
      for (int r = 0; r < 4; ++r) {
        if (OUT_BF16) ((u16*)Cout)[(size_t)(r0 + r) * N + c] = f2bf(acc[i][j][r]);
        else          ((float*)Cout)[(size_t)(r0 + r) * N + c] = acc[i][j][r];
      }
    }
  }
}

// ---------- decay scan, 3-phase chunked (C-buffers are bf16 z-values) ----------
__global__ void scan_p1(const u16* __restrict__ Cg, const u16* __restrict__ Cv,
                        const float* __restrict__ bg, float* __restrict__ E) {
  int tid = blockIdx.x * blockDim.x + threadIdx.x;  // B_*NC*M_
  int m = tid & (M_ - 1);
  int bc = tid >> 11;
  int c = bc & (NC - 1);
  int b = bc >> 5;
  float bgm = bg[m];
  size_t base = ((size_t)b * S_ + (size_t)c * CH) * M_ + m;
  float e = 0.f;
  #pragma unroll 4
  for (int s = 0; s < CH; ++s) {
    size_t o = base + (size_t)s * M_;
    float st = bf2f(Cv[o]) * sigmoidf_(bf2f(Cg[o]) + bgm) * SCALEF;
    e = fmaf(DECAYF, e, st);
  }
  E[(size_t)(b * M_ + m) * NC + c] = e;
}

__global__ void scan_p2(const float* __restrict__ E, float* __restrict__ P, float dch) {
  int tid = blockIdx.x * blockDim.x + threadIdx.x;  // B_*M_
  if (tid >= B_ * M_) return;
  size_t base = (size_t)tid * NC;
  float p = 0.f;
  for (int c = 0; c < NC; ++c) {
    P[base + c] = p;                    // carry INTO chunk c
    p = E[base + c] + dch * p;
  }
}

__global__ void scan_p3(const u16* __restrict__ Cg, const u16* __restrict__ Cv,
                        const u16* __restrict__ Cq, const float* __restrict__ bg,
                        const float* __restrict__ bq, const float* __restrict__ P,
                        u16* __restrict__ Lhi) {
  int tid = blockIdx.x * blockDim.x + threadIdx.x;
  int m = tid & (M_ - 1);
  int bc = tid >> 11;
  int c = bc & (NC - 1);
  int b = bc >> 5;
  float bgm = bg[m], bqm = bq[m];
  float mem = P[(size_t)(b * M_ + m) * NC + c];
  size_t base = ((size_t)b * S_ + (size_t)c * CH) * M_ + m;
  #pragma unroll 4
  for (int s = 0; s < CH; ++s) {
    size_t o = base + (size_t)s * M_;
    float st = bf2f(Cv[o]) * sigmoidf_(bf2f(Cg[o]) + bgm) * SCALEF;
    mem = fmaf(DECAYF, mem, st);
    float ld = mem * sigmoidf_(bf2f(Cq[o]) + bqm) * SCALEF;
    Lhi[o] = f2bf(ld);
  }
}

extern "C" void kernel_launch(void* const* d_in, const int* in_sizes, int n_in,
                              void* d_out, int out_size, void* d_ws, size_t ws_size,
                              hipStream_t stream) {
  const float* x  = (const float*)d_in[0];
  const float* Wv = (const float*)d_in[1];
  const float* Wg = (const float*)d_in[2];
  const float* bg = (const float*)d_in[3];
  const float* Wq = (const float*)d_in[4];
  const float* bq = (const float*)d_in[5];
  const float* Wo = (const float*)d_in[6];
  float* out = (float*)d_out;

  const size_t NXE = (size_t)ROWS * E_;   // 33.5M elems
  const size_t NW  = (size_t)E_ * M_;     // 4.2M elems

  char* ws = (char*)d_ws;
  size_t off = 0;
  auto alloc = [&](size_t bytes) -> void* {
    void* p = ws + off;
    off += (bytes + 255) & ~(size_t)255;
    return p;
  };
  // ---- core allocations (~270 MB) ----
  u16* x_hi   = (u16*)alloc(NXE * 2);     // aliased as Lhi after projections
  u16* Wgt_hi = (u16*)alloc(NW * 2);
  u16* Wgt_lo = (u16*)alloc(NW * 2);
  u16* Wvt_hi = (u16*)alloc(NW * 2);
  u16* Wvt_lo = (u16*)alloc(NW * 2);
  u16* Wqt_hi = (u16*)alloc(NW * 2);
  u16* Wqt_lo = (u16*)alloc(NW * 2);
  u16* Wot_hi = (u16*)alloc(NW * 2);
  u16* Wot_lo = (u16*)alloc(NW * 2);
  u16* Cg16   = (u16*)alloc(NXE * 2);
  u16* Cv16   = (u16*)alloc(NXE * 2);
  float* Ebuf = (float*)alloc((size_t)B_ * M_ * NC * 4);
  float* Pbuf = (float*)alloc((size_t)B_ * M_ * NC * 4);
  if (off > ws_size) {                    // ws < ~270MB: loud failure
    beacon_kernel<<<1, 256, 0, stream>>>(out);
    return;
  }
  // ---- tier 1: Cq16 in ws if it fits, else in d_out (consumed before GEMM4 writes) ----
  u16* Cq16;
  if (off + NXE * 2 <= ws_size) Cq16 = (u16*)alloc(NXE * 2);
  else                          Cq16 = (u16*)d_out;   // 67MB < 128MB out buffer
  // ---- tier 2: x_lo (3-term projections) if it fits ----
  u16* x_lo = nullptr;
  if (off + NXE * 2 <= ws_size) x_lo = (u16*)alloc(NXE * 2);
  // Lhi aliases x_hi (x dead after the projection GEMMs)
  u16* Lhi = x_hi;

  // 1) precision-split inputs
  split_x_kernel<<<2048, 256, 0, stream>>>(x, x_hi, x_lo, NXE / 4);
  dim3 tg(E_ / 32, M_ / 32);
  splitT_kernel<<<tg, 256, 0, stream>>>(Wg, Wgt_hi, Wgt_lo);
  splitT_kernel<<<tg, 256, 0, stream>>>(Wv, Wvt_hi, Wvt_lo);
  splitT_kernel<<<tg, 256, 0, stream>>>(Wq, Wqt_hi, Wqt_lo);
  splitT_kernel<<<tg, 256, 0, stream>>>(Wo, Wot_hi, Wot_lo);

  // 2) three projection GEMMs -> bf16 z-buffers
  const int ngemm = (ROWS / 128) * (M_ / 128);   // 2048, % 8 == 0
  if (x_lo) {
    gemm_split_bt<3, true><<<ngemm, 256, 0, stream>>>(x_hi, x_lo, Wgt_hi, Wgt_lo, Cg16, ROWS, M_, E_);
    gemm_split_bt<3, true><<<ngemm, 256, 0, stream>>>(x_hi, x_lo, Wvt_hi, Wvt_lo, Cv16, ROWS, M_, E_);
    gemm_split_bt<3, true><<<ngemm, 256, 0, stream>>>(x_hi, x_lo, Wqt_hi, Wqt_lo, Cq16, ROWS, M_, E_);
  } else {
    gemm_split_bt<2, true><<<ngemm, 256, 0, stream>>>(x_hi, x_hi, Wgt_hi, Wgt_lo, Cg16, ROWS, M_, E_);
    gemm_split_bt<2, true><<<ngemm, 256, 0, stream>>>(x_hi, x_hi, Wvt_hi, Wvt_lo, Cv16, ROWS, M_, E_);
    gemm_split_bt<2, true><<<ngemm, 256, 0, stream>>>(x_hi, x_hi, Wqt_hi, Wqt_lo, Cq16, ROWS, M_, E_);
  }

  // 3) fused gate/store -> chunked decay scan -> que/load (bf16, into Lhi==x_hi)
  scan_p1<<<(B_ * NC * M_) / 256, 256, 0, stream>>>(Cg16, Cv16, bg, Ebuf);
  scan_p2<<<(B_ * M_ + 255) / 256, 256, 0, stream>>>(Ebuf, Pbuf, powf(DECAYF, (float)CH));
  scan_p3<<<(B_ * NC * M_) / 256, 256, 0, stream>>>(Cg16, Cv16, Cq16, bg, bq, Pbuf, Lhi);

  // 4) output projection (fp32 out, 2-term: L*Wo_hi + L*Wo_lo)
  gemm_split_bt<2, false><<<ngemm, 256, 0, stream>>>(Lhi, Lhi, Wot_hi, Wot_lo, out, ROWS, E_, M_);
}

// Round 7
// 1639.578 us; speedup vs baseline: 1.5844x; 1.0841x over previous
//
#include <hip/hip_runtime.h>
#include <math.h>

#define B_  4
#define S_  4096
#define E_  2048
#define M_  2048
#define ROWS (B_*S_)              // 16384
#define DECAYF 0.95f
#define SCALEF 0.22360679774997896f   // sqrt(1-0.95)
#define CH 128
#define NC 32                     // S_/CH

typedef __attribute__((ext_vector_type(8))) __bf16 bf16x8;
typedef __attribute__((ext_vector_type(4))) float f32x4;
typedef unsigned short u16;

__device__ __forceinline__ u16 f2bf(float f) {
  unsigned u = __float_as_uint(f);
  u += 0x7FFF + ((u >> 16) & 1);      // RNE
  return (u16)(u >> 16);
}
__device__ __forceinline__ float bf2f(u16 h) {
  return __uint_as_float(((unsigned)h) << 16);
}
__device__ __forceinline__ float sigmoidf_(float x) {
  return 1.0f / (1.0f + expf(-x));
}

// ---------- beacon: ws too small -> unmistakable absmax ~1e6 ----------
__global__ void beacon_kernel(float* __restrict__ out) {
  out[threadIdx.x] = 1.0e6f;
}

// ---------- split x (fp32) -> bf16 hi (+ optional lo) ----------
__global__ void split_x_kernel(const float* __restrict__ x, u16* __restrict__ hi,
                               u16* __restrict__ lo, size_t n4) {
  size_t i = (size_t)blockIdx.x * blockDim.x + threadIdx.x;
  size_t stride = (size_t)gridDim.x * blockDim.x;
  const float4* x4 = (const float4*)x;
  for (; i < n4; i += stride) {
    float4 v = x4[i];
    u16 h0 = f2bf(v.x), h1 = f2bf(v.y), h2 = f2bf(v.z), h3 = f2bf(v.w);
    ushort4 hv = {h0, h1, h2, h3};
    ((ushort4*)hi)[i] = hv;
    if (lo) {
      ushort4 lv = {f2bf(v.x - bf2f(h0)), f2bf(v.y - bf2f(h1)),
                    f2bf(v.z - bf2f(h2)), f2bf(v.w - bf2f(h3))};
      ((ushort4*)lo)[i] = lv;
    }
  }
}

// ---------- transpose + split W[K][N] fp32 -> Wt_hi/lo [N][K] bf16 ----------
__global__ void splitT_kernel(const float* __restrict__ W, u16* __restrict__ th,
                              u16* __restrict__ tl) {
  __shared__ float tile[32][33];
  int k0 = blockIdx.x * 32, n0 = blockIdx.y * 32;
  int tx = threadIdx.x & 31, ty = threadIdx.x >> 5;   // 256 threads
  #pragma unroll
  for (int i = ty; i < 32; i += 8)
    tile[i][tx] = W[(size_t)(k0 + i) * M_ + (n0 + tx)];
  __syncthreads();
  #pragma unroll
  for (int i = ty; i < 32; i += 8) {
    float v = tile[tx][i];                 // = W[k0+tx][n0+i]
    size_t o = (size_t)(n0 + i) * E_ + (k0 + tx);
    u16 h = f2bf(v);
    th[o] = h;
    tl[o] = f2bf(v - bf2f(h));
  }
}

// ---------- 256^2-tile split-bf16 GEMM: virtual-K term-major, dbuf LDS, ----------
// ---------- slot-XOR conflict-free swizzle, stage-before-compute (T2/T3/T5) -----
// Virtual K = NTERMS*K, term-major:
//   NTERMS==3: (A0,B0),(A1,B0),(A0,B1)   ~fp32 accurate
//   NTERMS==2: (A0,B0),(A0,B1)
// A: [Mrows][K] bf16, B: [N][K] bf16. BM=BN=256, BK=64, 512 thr (8 waves 2x4).
// LDS: 2 dbuf x (A 32KB + B 32KB) = 128 KiB -> 1 block/CU.
// Swizzle: 16B unit (row,slot) stored at slot^(row&7); staging pre-swizzles the
// GLOBAL source col (global_load_lds dest stays linear), ds_read applies same XOR.
template<int NTERMS, bool OUT_BF16>
__global__ __launch_bounds__(512) void gemm256(
    const u16* __restrict__ A0, const u16* __restrict__ A1,
    const u16* __restrict__ B0, const u16* __restrict__ B1,
    void* __restrict__ Cout, int Mrows, int N, int K) {
  __shared__ __align__(16) u16 sm[2][2][256 * 64];   // [buf][A/B][tile]

  // bijective XCD swizzle (gridDim.x % 8 == 0), bn fastest within an XCD
  const int cpx = gridDim.x >> 3;
  const int swz = (blockIdx.x & 7) * cpx + (blockIdx.x >> 3);
  const int ntiles = N >> 8;
  const int bm = (swz / ntiles) << 8;
  const int bn = (swz % ntiles) << 8;

  const int t = threadIdx.x;
  const int w = t >> 6, lane = t & 63;
  const int wr = w >> 2, wc = w & 3;          // 2x4 wave grid: 128x64 out/wave
  const int lr = lane & 15, s4 = lane >> 4;   // fragment row, k-slot
  const int rsw = lr & 7;                     // read-side slot XOR

  // staging: thread t covers linear LDS pos t*16B of each 8KB chunk j.
  // linear pos -> (row = j*64 + w*8 + (lane>>3), stored slot = lane&7).
  // stored slot st holds logical slot st ^ (row&7) -> fetch that from global.
  const int srow = w * 8 + (lane >> 3);
  const int scol = ((lane & 7) ^ ((lane >> 3) & 7)) << 3;   // u16 col

  f32x4 acc[8][4];
  #pragma unroll
  for (int i = 0; i < 8; ++i)
    #pragma unroll
    for (int j = 0; j < 4; ++j)
      acc[i][j] = f32x4{0.f, 0.f, 0.f, 0.f};

  const int KT = K >> 6;              // K-tiles per term
  const int NKT = KT * NTERMS;

  const u16* Ag = A0;
  const u16* Bg = B0;
  int kt = 0, term = 0;
  auto advance = [&]() {              // move staging counters to next v-tile
    if (++kt == KT) {
      kt = 0; ++term;
      if (NTERMS == 3) { Ag = (term == 1) ? A1 : A0; Bg = (term == 2) ? B1 : B0; }
      else             { Bg = B1; }
    }
  };
  auto stage = [&](u16* dA, u16* dB) {
    const int kk = kt << 6;
    #pragma unroll
    for (int j = 0; j < 4; ++j) {
      __builtin_amdgcn_global_load_lds(
          (const __attribute__((address_space(1))) unsigned int*)
              (Ag + (size_t)(bm + j * 64 + srow) * K + kk + scol),
          (__attribute__((address_space(3))) unsigned int*)(dA + j * 4096 + w * 512),
          16, 0, 0);
      __builtin_amdgcn_global_load_lds(
          (const __attribute__((address_space(1))) unsigned int*)
              (Bg + (size_t)(bn + j * 64 + srow) * K + kk + scol),
          (__attribute__((address_space(3))) unsigned int*)(dB + j * 4096 + w * 512),
          16, 0, 0);
    }
  };

  stage(sm[0][0], sm[0][1]);
  advance();
  __syncthreads();                    // drains vmcnt(0): tile 0 resident

  int cur = 0;
  for (int vt = 0; vt < NKT; ++vt) {
    if (vt + 1 < NKT) {               // issue next tile FIRST (overlaps compute)
      stage(sm[cur ^ 1][0], sm[cur ^ 1][1]);
      advance();
    }
    const u16* cA = sm[cur][0];
    const u16* cB = sm[cur][1];
    // B-fragments for the whole tile (4 cols x 2 ksteps)
    bf16x8 bf[4][2];
    #pragma unroll
    for (int ci = 0; ci < 4; ++ci)
      #pragma unroll
      for (int h = 0; h < 2; ++h) {
        const int r = wc * 64 + ci * 16 + lr;
        const int sl = h * 4 + s4;
        bf[ci][h] = *(const bf16x8*)&cB[r * 64 + ((sl ^ rsw) << 3)];
      }
    #pragma unroll
    for (int ph = 0; ph < 4; ++ph) {
      bf16x8 af[2][2];
      #pragma unroll
      for (int rr = 0; rr < 2; ++rr)
        #pragma unroll
        for (int h = 0; h < 2; ++h) {
          const int r = wr * 128 + (ph * 2 + rr) * 16 + lr;
          const int sl = h * 4 + s4;
          af[rr][h] = *(const bf16x8*)&cA[r * 64 + ((sl ^ rsw) << 3)];
        }
      __builtin_amdgcn_s_setprio(1);
      #pragma unroll
      for (int rr = 0; rr < 2; ++rr)
        #pragma unroll
        for (int ci = 0; ci < 4; ++ci)
          #pragma unroll
          for (int h = 0; h < 2; ++h)
            acc[ph * 2 + rr][ci] = __builtin_amdgcn_mfma_f32_16x16x32_bf16(
                af[rr][h], bf[ci][h], acc[ph * 2 + rr][ci], 0, 0, 0);
      __builtin_amdgcn_s_setprio(0);
    }
    __syncthreads();                  // all reads done + next tile drained
    cur ^= 1;
  }

  // epilogue: C/D layout col=lane&15, row=(lane>>4)*4+reg  [m89-verified]
  #pragma unroll
  for (int ri = 0; ri < 8; ++ri)
    #pragma unroll
    for (int ci = 0; ci < 4; ++ci) {
      const int r0 = bm + wr * 128 + ri * 16 + s4 * 4;
      const int c  = bn + wc * 64 + ci * 16 + lr;
      #pragma unroll
      for (int r = 0; r < 4; ++r) {
        if (OUT_BF16) ((u16*)Cout)[(size_t)(r0 + r) * N + c] = f2bf(acc[ri][ci][r]);
        else          ((float*)Cout)[(size_t)(r0 + r) * N + c] = acc[ri][ci][r];
      }
    }
}

// ---------- decay scan, 3-phase chunked (C-buffers are bf16 z-values) ----------
__global__ void scan_p1(const u16* __restrict__ Cg, const u16* __restrict__ Cv,
                        const float* __restrict__ bg, float* __restrict__ E) {
  int tid = blockIdx.x * blockDim.x + threadIdx.x;  // B_*NC*M_
  int m = tid & (M_ - 1);
  int bc = tid >> 11;
  int c = bc & (NC - 1);
  int b = bc >> 5;
  float bgm = bg[m];
  size_t base = ((size_t)b * S_ + (size_t)c * CH) * M_ + m;
  float e = 0.f;
  #pragma unroll 4
  for (int s = 0; s < CH; ++s) {
    size_t o = base + (size_t)s * M_;
    float st = bf2f(Cv[o]) * sigmoidf_(bf2f(Cg[o]) + bgm) * SCALEF;
    e = fmaf(DECAYF, e, st);
  }
  E[(size_t)(b * M_ + m) * NC + c] = e;
}

__global__ void scan_p2(const float* __restrict__ E, float* __restrict__ P, float dch) {
  int tid = blockIdx.x * blockDim.x + threadIdx.x;  // B_*M_
  if (tid >= B_ * M_) return;
  size_t base = (size_t)tid * NC;
  float p = 0.f;
  for (int c = 0; c < NC; ++c) {
    P[base + c] = p;                    // carry INTO chunk c
    p = E[base + c] + dch * p;
  }
}

__global__ void scan_p3(const u16* __restrict__ Cg, const u16* __restrict__ Cv,
                        const u16* __restrict__ Cq, const float* __restrict__ bg,
                        const float* __restrict__ bq, const float* __restrict__ P,
                        u16* __restrict__ Lhi) {
  int tid = blockIdx.x * blockDim.x + threadIdx.x;
  int m = tid & (M_ - 1);
  int bc = tid >> 11;
  int c = bc & (NC - 1);
  int b = bc >> 5;
  float bgm = bg[m], bqm = bq[m];
  float mem = P[(size_t)(b * M_ + m) * NC + c];
  size_t base = ((size_t)b * S_ + (size_t)c * CH) * M_ + m;
  #pragma unroll 4
  for (int s = 0; s < CH; ++s) {
    size_t o = base + (size_t)s * M_;
    float st = bf2f(Cv[o]) * sigmoidf_(bf2f(Cg[o]) + bgm) * SCALEF;
    mem = fmaf(DECAYF, mem, st);
    float ld = mem * sigmoidf_(bf2f(Cq[o]) + bqm) * SCALEF;
    Lhi[o] = f2bf(ld);
  }
}

extern "C" void kernel_launch(void* const* d_in, const int* in_sizes, int n_in,
                              void* d_out, int out_size, void* d_ws, size_t ws_size,
                              hipStream_t stream) {
  const float* x  = (const float*)d_in[0];
  const float* Wv = (const float*)d_in[1];
  const float* Wg = (const float*)d_in[2];
  const float* bg = (const float*)d_in[3];
  const float* Wq = (const float*)d_in[4];
  const float* bq = (const float*)d_in[5];
  const float* Wo = (const float*)d_in[6];
  float* out = (float*)d_out;

  const size_t NXE = (size_t)ROWS * E_;   // 33.5M elems
  const size_t NW  = (size_t)E_ * M_;     // 4.2M elems

  char* ws = (char*)d_ws;
  size_t off = 0;
  auto alloc = [&](size_t bytes) -> void* {
    void* p = ws + off;
    off += (bytes + 255) & ~(size_t)255;
    return p;
  };
  // ---- core allocations (~270 MB) ----
  u16* x_hi   = (u16*)alloc(NXE * 2);     // aliased as Lhi after projections
  u16* Wgt_hi = (u16*)alloc(NW * 2);
  u16* Wgt_lo = (u16*)alloc(NW * 2);
  u16* Wvt_hi = (u16*)alloc(NW * 2);
  u16* Wvt_lo = (u16*)alloc(NW * 2);
  u16* Wqt_hi = (u16*)alloc(NW * 2);
  u16* Wqt_lo = (u16*)alloc(NW * 2);
  u16* Wot_hi = (u16*)alloc(NW * 2);
  u16* Wot_lo = (u16*)alloc(NW * 2);
  u16* Cg16   = (u16*)alloc(NXE * 2);
  u16* Cv16   = (u16*)alloc(NXE * 2);
  float* Ebuf = (float*)alloc((size_t)B_ * M_ * NC * 4);
  float* Pbuf = (float*)alloc((size_t)B_ * M_ * NC * 4);
  if (off > ws_size) {                    // ws < ~270MB: loud failure
    beacon_kernel<<<1, 256, 0, stream>>>(out);
    return;
  }
  // ---- tier 1: Cq16 in ws if it fits, else in d_out (consumed before GEMM4 writes) ----
  u16* Cq16;
  if (off + NXE * 2 <= ws_size) Cq16 = (u16*)alloc(NXE * 2);
  else                          Cq16 = (u16*)d_out;   // 67MB < 128MB out buffer
  // ---- tier 2: x_lo (3-term projections) if it fits ----
  u16* x_lo = nullptr;
  if (off + NXE * 2 <= ws_size) x_lo = (u16*)alloc(NXE * 2);
  // Lhi aliases x_hi (x dead after the projection GEMMs)
  u16* Lhi = x_hi;

  // 1) precision-split inputs
  split_x_kernel<<<2048, 256, 0, stream>>>(x, x_hi, x_lo, NXE / 4);
  dim3 tg(E_ / 32, M_ / 32);
  splitT_kernel<<<tg, 256, 0, stream>>>(Wg, Wgt_hi, Wgt_lo);
  splitT_kernel<<<tg, 256, 0, stream>>>(Wv, Wvt_hi, Wvt_lo);
  splitT_kernel<<<tg, 256, 0, stream>>>(Wq, Wqt_hi, Wqt_lo);
  splitT_kernel<<<tg, 256, 0, stream>>>(Wo, Wot_hi, Wot_lo);

  // 2) three projection GEMMs -> bf16 z-buffers (256^2 tiles: 64x8 = 512 blocks)
  const int ngemm = (ROWS / 256) * (M_ / 256);   // 512, % 8 == 0
  if (x_lo) {
    gemm256<3, true><<<ngemm, 512, 0, stream>>>(x_hi, x_lo, Wgt_hi, Wgt_lo, Cg16, ROWS, M_, E_);
    gemm256<3, true><<<ngemm, 512, 0, stream>>>(x_hi, x_lo, Wvt_hi, Wvt_lo, Cv16, ROWS, M_, E_);
    gemm256<3, true><<<ngemm, 512, 0, stream>>>(x_hi, x_lo, Wqt_hi, Wqt_lo, Cq16, ROWS, M_, E_);
  } else {
    gemm256<2, true><<<ngemm, 512, 0, stream>>>(x_hi, x_hi, Wgt_hi, Wgt_lo, Cg16, ROWS, M_, E_);
    gemm256<2, true><<<ngemm, 512, 0, stream>>>(x_hi, x_hi, Wvt_hi, Wvt_lo, Cv16, ROWS, M_, E_);
    gemm256<2, true><<<ngemm, 512, 0, stream>>>(x_hi, x_hi, Wqt_hi, Wqt_lo, Cq16, ROWS, M_, E_);
  }

  // 3) fused gate/store -> chunked decay scan -> que/load (bf16, into Lhi==x_hi)
  scan_p1<<<(B_ * NC * M_) / 256, 256, 0, stream>>>(Cg16, Cv16, bg, Ebuf);
  scan_p2<<<(B_ * M_ + 255) / 256, 256, 0, stream>>>(Ebuf, Pbuf, powf(DECAYF, (float)CH));
  scan_p3<<<(B_ * NC * M_) / 256, 256, 0, stream>>>(Cg16, Cv16, Cq16, bg, bq, Pbuf, Lhi);

  // 4) output projection (fp32 out, 2-term: L*Wo_hi + L*Wo_lo)
  gemm256<2, false><<<ngemm, 512, 0, stream>>>(Lhi, Lhi, Wot_hi, Wot_lo, out, ROWS, E_, M_);
}